// Round 5
// baseline (188.526 us; speedup 1.0000x reference)
//
#include <hip/hip_runtime.h>
#include <math.h>

#define L_SEQ 512
#define BSZ 2
#define NH 8
#define HD 32
#define E 256
#define SCALE 0.17677669529663687f
#define SROW 520   // s_lds row stride (floats): 520%32==8 -> 2-way bank alias (free)

typedef float f32x4 __attribute__((ext_vector_type(4)));

// DPP add: result = x + lanes-permuted x (VALU pipe, no DS ops)
template <int CTRL>
__device__ __forceinline__ float dpp_add(float x) {
    return x + __int_as_float(
        __builtin_amdgcn_update_dpp(0, __float_as_int(x), CTRL, 0xF, 0xF, true));
}
// full sum over each 8-lane octet, result in ALL lanes of the octet
__device__ __forceinline__ float octet_allsum(float x) {
    x = dpp_add<0xB1>(x);    // quad_perm(1,0,3,2)  : xor 1
    x = dpp_add<0x4E>(x);    // quad_perm(2,3,0,1)  : xor 2
    x = dpp_add<0x141>(x);   // row_half_mirror     : pairs quads 0-3 <-> 4-7
    return x;
}

// Workspace layouts:
//   q2     : (B, L, E)       1KB row per (b,l)
//   kh, vh : (B*NH, L, HD)   head-major
//   oh2    : (B, L, E)
//   scores : (B*NH, L, L)    qk*SCALE + mask, precomputed

// ---------------- Kernel 1: in-projection ----------------
__global__ void inproj_kernel(const float* __restrict__ query,
                              const float* __restrict__ W,
                              const float* __restrict__ bias,
                              float* __restrict__ q2,
                              float* __restrict__ kh,
                              float* __restrict__ vh) {
    int r0 = blockIdx.x * 4;         // rows r0..r0+3 (row = l*B + b)
    int y  = blockIdx.y;             // 0/1 -> passes y*4 .. y*4+3
    int t = threadIdx.x;             // 0..255
    __shared__ float xs[4][E];
#pragma unroll
    for (int r = 0; r < 4; ++r) xs[r][t] = query[(size_t)(r0 + r) * E + t];
    __syncthreads();

    int c = t & 7, cg = t >> 3;
#pragma unroll
    for (int pp = 0; pp < 4; ++pp) {
        int pass = y * 4 + pp;
        int col = pass * 32 + cg;    // 0..255 within each part
        float a[3][4];
#pragma unroll
        for (int p = 0; p < 3; ++p)
#pragma unroll
            for (int r = 0; r < 4; ++r) a[p][r] = 0.f;

#pragma unroll
        for (int kk = 0; kk < 8; ++kk) {
            float4 x0 = ((const float4*)xs[0])[c + kk * 8];
            float4 x1 = ((const float4*)xs[1])[c + kk * 8];
            float4 x2 = ((const float4*)xs[2])[c + kk * 8];
            float4 x3 = ((const float4*)xs[3])[c + kk * 8];
#pragma unroll
            for (int p = 0; p < 3; ++p) {
                float4 w = ((const float4*)(W + (size_t)(p * E + col) * E))[c + kk * 8];
                a[p][0] += w.x * x0.x + w.y * x0.y + w.z * x0.z + w.w * x0.w;
                a[p][1] += w.x * x1.x + w.y * x1.y + w.z * x1.z + w.w * x1.w;
                a[p][2] += w.x * x2.x + w.y * x2.y + w.z * x2.z + w.w * x2.w;
                a[p][3] += w.x * x3.x + w.y * x3.y + w.z * x3.z + w.w * x3.w;
            }
        }
#pragma unroll
        for (int p = 0; p < 3; ++p)
#pragma unroll
            for (int r = 0; r < 4; ++r) a[p][r] = octet_allsum(a[p][r]);

        if (c == 0) {
#pragma unroll
            for (int p = 0; p < 3; ++p) {
                float bb = bias[p * E + col];
#pragma unroll
                for (int r = 0; r < 4; ++r) {
                    int row = r0 + r, l = row >> 1, b = row & 1;
                    float val = a[p][r] + bb;
                    if (p == 0) {
                        q2[((size_t)b * L_SEQ + l) * E + col] = val;
                    } else {
                        int h = col >> 5, d = col & 31;
                        float* dst = (p == 1) ? kh : vh;
                        dst[((size_t)(b * NH + h) * L_SEQ + l) * HD + d] = val;
                    }
                }
            }
        }
    }
}

// ---------------- Kernel 2: QK^T * scale + mask -> scores ----------------
// Block = (head n, 32 q-rows). k rows live in registers (2/lane), q broadcast
// from LDS. All traffic is L2-resident (kh 2MB, q2 2MB); writes 16MB coalesced.
__global__ void qk_kernel(const float* __restrict__ q2,
                          const float* __restrict__ kh,
                          const float* __restrict__ mask,
                          float* __restrict__ scores) {
    int n = blockIdx.x;              // 0..15
    int b = n >> 3, h = n & 7;
    int l0 = blockIdx.y * 32;
    int t = threadIdx.x, lane = t & 63, w = t >> 6;

    __shared__ float qs[32][32];
    {
        int row = t >> 3, quad = t & 7;
        float4 qv = *(const float4*)(q2 + ((size_t)b * L_SEQ + l0 + row) * E + h * HD + quad * 4);
        ((float4*)qs[row])[quad] = qv;
    }
    __syncthreads();

    // k rows in registers: m_a = w*128 + lane, m_b = m_a + 64
    f32x4 ka[8], kb[8];
    const float* kbase = kh + (size_t)n * L_SEQ * HD;
    {
        const f32x4* pa = (const f32x4*)(kbase + (size_t)(w * 128 + lane) * HD);
        const f32x4* pb = (const f32x4*)(kbase + (size_t)(w * 128 + 64 + lane) * HD);
#pragma unroll
        for (int i = 0; i < 8; ++i) { ka[i] = pa[i]; kb[i] = pb[i]; }
    }

    for (int li = 0; li < 32; ++li) {
        int l = l0 + li;
        float da = 0.f, db = 0.f;
#pragma unroll
        for (int i = 0; i < 8; ++i) {
            float4 qv = ((const float4*)qs[li])[i];
            da += ka[i].x * qv.x + ka[i].y * qv.y + ka[i].z * qv.z + ka[i].w * qv.w;
            db += kb[i].x * qv.x + kb[i].y * qv.y + kb[i].z * qv.z + kb[i].w * qv.w;
        }
        size_t off = ((size_t)n * L_SEQ + l) * L_SEQ;
        const float* mrow = mask + (size_t)l * L_SEQ;
        scores[off + w * 128 + lane]      = da * SCALE + mrow[w * 128 + lane];
        scores[off + w * 128 + 64 + lane] = db * SCALE + mrow[w * 128 + 64 + lane];
    }
}

// ---------------- Kernel 3: rel-bias stream + softmax + PV ----------------
// One block per (b,l), 512 threads = 8 waves. Phase 1 streams ONLY rpe
// (1KB contiguous per wave-instruction); octet reduce is pure-VALU DPP;
// one LDS write per 8 rows. Wave w owns head w for softmax + PV.
__global__ void attn_kernel(const float* __restrict__ q2,
                            const float* __restrict__ vh,
                            const float* __restrict__ rpe,
                            const float* __restrict__ scores,
                            float* __restrict__ attn_out,
                            float* __restrict__ oh2) {
    int bid = blockIdx.x;            // b*512 + l
    int b = bid >> 9, l = bid & (L_SEQ - 1);
    int t = threadIdx.x;
    int lane = t & 63, wid = t >> 6;

    __shared__ float qs[E];
    __shared__ float s_lds[NH * SROW];   // rel partial sums -> later attn probs

    if (t < E) qs[t] = q2[((size_t)b * L_SEQ + l) * E + t];
    __syncthreads();

    // ---- Phase 1: rel bias. Wave w streams rows m = w*64..w*64+63 (64KB). ----
    f32x4 qc = ((const f32x4*)qs)[lane];   // lane covers head lane>>3, quad lane&7
    int csel = lane & 7, h1 = lane >> 3;
    const float* rbase = rpe + ((size_t)(b * L_SEQ + l)) * L_SEQ * E;

    for (int ii = 0; ii < 8; ++ii) {
        float keep = 0.f;
#pragma unroll
        for (int i8 = 0; i8 < 8; ++i8) {
            int m = wid * 64 + ii * 8 + i8;
            f32x4 rv = __builtin_nontemporal_load(((const f32x4*)(rbase + (size_t)m * E)) + lane);
            float part = rv.x * qc.x + rv.y * qc.y + rv.z * qc.z + rv.w * qc.w;
            part = octet_allsum(part);        // all 8 lanes of octet hold row-sum
            keep = (i8 == csel) ? part : keep; // lane stashes row (ii*8 + csel)
        }
        s_lds[h1 * SROW + wid * 64 + ii * 8 + csel] = keep;  // 64 distinct slots
    }
    __syncthreads();

    // ---- Phase 2: softmax. Wave w owns head w. ----
    int h = wid;
    const float* srow = scores + ((size_t)(b * NH + h) * L_SEQ + l) * L_SEQ;
    float sv[8];
    float mx = -1e30f;
#pragma unroll
    for (int i = 0; i < 8; ++i) {
        int m = i * 64 + lane;
        sv[i] = s_lds[h * SROW + m] + srow[m];   // rel + (qk*scale + mask)
        mx = fmaxf(mx, sv[i]);
    }
#pragma unroll
    for (int off = 32; off > 0; off >>= 1) mx = fmaxf(mx, __shfl_xor(mx, off));
    float sum = 0.f;
#pragma unroll
    for (int i = 0; i < 8; ++i) { sv[i] = __expf(sv[i] - mx); sum += sv[i]; }
#pragma unroll
    for (int off = 32; off > 0; off >>= 1) sum += __shfl_xor(sum, off);
    float inv = 1.0f / sum;

    float* arow = attn_out + ((size_t)(b * NH + h) * L_SEQ + l) * L_SEQ;
#pragma unroll
    for (int i = 0; i < 8; ++i) {
        int m = i * 64 + lane;
        float pn = sv[i] * inv;
        arow[m] = pn;
        s_lds[h * SROW + m] = pn;   // wave-local reuse below
    }

    // ---- Phase 3: PV for head h (wave-local). ----
    int dq = lane & 7, mg = lane >> 3;
    const f32x4* vbase = (const f32x4*)(vh + (size_t)(b * NH + h) * L_SEQ * HD);
    float4 acc = {0.f, 0.f, 0.f, 0.f};
#pragma unroll 4
    for (int i = 0; i < 64; ++i) {
        int m = i * 8 + mg;
        f32x4 v4 = vbase[(size_t)m * 8 + dq];
        float p = s_lds[h * SROW + m];
        acc.x += p * v4.x; acc.y += p * v4.y; acc.z += p * v4.z; acc.w += p * v4.w;
    }
#pragma unroll
    for (int off = 8; off <= 32; off <<= 1) {
        acc.x += __shfl_xor(acc.x, off);
        acc.y += __shfl_xor(acc.y, off);
        acc.z += __shfl_xor(acc.z, off);
        acc.w += __shfl_xor(acc.w, off);
    }
    if (mg == 0) {
        ((float4*)(oh2 + ((size_t)b * L_SEQ + l) * E))[h * 8 + dq] = acc;
    }
}

// ---------------- Kernel 4: out-projection ----------------
__global__ void outproj_kernel(const float* __restrict__ oh2,
                               const float* __restrict__ W,
                               const float* __restrict__ bias,
                               float* __restrict__ out) {
    int r0 = blockIdx.x * 4;
    int y  = blockIdx.y;             // 0/1 -> passes y*4 .. y*4+3
    int t = threadIdx.x;             // 0..255
    __shared__ float xs[4][E];
#pragma unroll
    for (int r = 0; r < 4; ++r) {
        int row = r0 + r, l = row >> 1, b = row & 1;
        xs[r][t] = oh2[((size_t)b * L_SEQ + l) * E + t];
    }
    __syncthreads();

    int c = t & 7, cg = t >> 3;
#pragma unroll
    for (int pp = 0; pp < 4; ++pp) {
        int pass = y * 4 + pp;
        int col = pass * 32 + cg;
        const float4* wp = (const float4*)(W + (size_t)col * E);
        float a0 = 0.f, a1 = 0.f, a2 = 0.f, a3 = 0.f;
#pragma unroll
        for (int kk = 0; kk < 8; ++kk) {
            float4 w  = wp[c + kk * 8];
            float4 x0 = ((const float4*)xs[0])[c + kk * 8];
            float4 x1 = ((const float4*)xs[1])[c + kk * 8];
            float4 x2 = ((const float4*)xs[2])[c + kk * 8];
            float4 x3 = ((const float4*)xs[3])[c + kk * 8];
            a0 += w.x * x0.x + w.y * x0.y + w.z * x0.z + w.w * x0.w;
            a1 += w.x * x1.x + w.y * x1.y + w.z * x1.z + w.w * x1.w;
            a2 += w.x * x2.x + w.y * x2.y + w.z * x2.z + w.w * x2.w;
            a3 += w.x * x3.x + w.y * x3.y + w.z * x3.z + w.w * x3.w;
        }
        a0 = octet_allsum(a0); a1 = octet_allsum(a1);
        a2 = octet_allsum(a2); a3 = octet_allsum(a3);
        if (c == 0) {
            float bb = bias[col];
            float res[4] = {a0, a1, a2, a3};
#pragma unroll
            for (int r = 0; r < 4; ++r) {
                out[(size_t)(r0 + r) * E + col] = res[r] + bb;
            }
        }
    }
}

extern "C" void kernel_launch(void* const* d_in, const int* in_sizes, int n_in,
                              void* d_out, int out_size, void* d_ws, size_t ws_size,
                              hipStream_t stream) {
    const float* query = (const float*)d_in[0];
    // d_in[1] = key, d_in[2] = value -- UNUSED by the reference (it projects only query)
    const float* rpe   = (const float*)d_in[3];
    const float* mask  = (const float*)d_in[4];
    const float* Win   = (const float*)d_in[5];
    const float* bin   = (const float*)d_in[6];
    const float* Wout  = (const float*)d_in[7];
    const float* bout  = (const float*)d_in[8];

    float* out  = (float*)d_out;                            // (L,B,E)
    float* attn = (float*)d_out + (size_t)L_SEQ * BSZ * E;  // (B*H,L,L)

    float* q2     = (float*)d_ws;                           // (B,L,E)
    float* kh     = q2  + (size_t)BSZ * L_SEQ * E;          // (B*H,L,D)
    float* vh     = kh  + (size_t)BSZ * NH * L_SEQ * HD;    // (B*H,L,D)
    float* oh2    = vh  + (size_t)BSZ * NH * L_SEQ * HD;    // (B,L,E)
    float* scores = oh2 + (size_t)BSZ * L_SEQ * E;          // (B*H,L,L)

    inproj_kernel<<<dim3((L_SEQ * BSZ) / 4, 2), E, 0, stream>>>(query, Win, bin, q2, kh, vh);
    qk_kernel<<<dim3(BSZ * NH, L_SEQ / 32), 256, 0, stream>>>(q2, kh, mask, scores);
    attn_kernel<<<BSZ * L_SEQ, 512, 0, stream>>>(q2, vh, rpe, scores, attn, oh2);
    outproj_kernel<<<dim3((L_SEQ * BSZ) / 4, 2), E, 0, stream>>>(oh2, Wout, bout, out);
}

// Round 6
// 167.644 us; speedup vs baseline: 1.1246x; 1.1246x over previous
//
#include <hip/hip_runtime.h>
#include <math.h>

#define L_SEQ 512
#define BSZ 2
#define NH 8
#define HD 32
#define E 256
#define SCALE 0.17677669529663687f
#define SROW 520   // s_lds row stride: (h*520+m)%32 = (h*8+m)%32 -> conflict-free patterns

typedef float f32x4 __attribute__((ext_vector_type(4)));

// Workspace:
//   q2     : (B, L, E)       1KB row per (b,l)
//   kh, vh : (B*NH, L, HD)   head-major
//   oh2    : (B, L, E)
//   scores : (B*NH, L, L)    qk*SCALE + mask

// ---------------- Kernel 1: in-projection ----------------
// grid (256 rowgrps, 12 colgrps) -> 3072 blocks (12/CU). Block: 4 rows x 64 cols.
__global__ void inproj_kernel(const float* __restrict__ query,
                              const float* __restrict__ W,
                              const float* __restrict__ bias,
                              float* __restrict__ q2,
                              float* __restrict__ kh,
                              float* __restrict__ vh) {
    int rg = blockIdx.x;             // rows rg*4 .. rg*4+3 (row = l*B + b)
    int cg3 = blockIdx.y;            // out-features cg3*64 .. +63 (of 768)
    int t = threadIdx.x;             // 0..255
    __shared__ float xs[4][E];
#pragma unroll
    for (int r = 0; r < 4; ++r) xs[r][t] = query[(size_t)(rg * 4 + r) * E + t];
    __syncthreads();

    int c = t & 7, cg = t >> 3;
#pragma unroll
    for (int pp = 0; pp < 2; ++pp) {
        int col768 = cg3 * 64 + pp * 32 + cg;
        const float4* wp = (const float4*)(W + (size_t)col768 * E);
        float a0 = 0.f, a1 = 0.f, a2 = 0.f, a3 = 0.f;
#pragma unroll
        for (int kk = 0; kk < 8; ++kk) {
            float4 w  = wp[c + kk * 8];
            float4 x0 = ((const float4*)xs[0])[c + kk * 8];
            float4 x1 = ((const float4*)xs[1])[c + kk * 8];
            float4 x2 = ((const float4*)xs[2])[c + kk * 8];
            float4 x3 = ((const float4*)xs[3])[c + kk * 8];
            a0 += w.x * x0.x + w.y * x0.y + w.z * x0.z + w.w * x0.w;
            a1 += w.x * x1.x + w.y * x1.y + w.z * x1.z + w.w * x1.w;
            a2 += w.x * x2.x + w.y * x2.y + w.z * x2.z + w.w * x2.w;
            a3 += w.x * x3.x + w.y * x3.y + w.z * x3.z + w.w * x3.w;
        }
#pragma unroll
        for (int off = 1; off <= 4; off <<= 1) {
            a0 += __shfl_xor(a0, off);
            a1 += __shfl_xor(a1, off);
            a2 += __shfl_xor(a2, off);
            a3 += __shfl_xor(a3, off);
        }
        if (c == 0) {
            int p = col768 >> 8, col = col768 & 255;
            float bb = bias[col768];
            float res[4] = {a0, a1, a2, a3};
#pragma unroll
            for (int r = 0; r < 4; ++r) {
                int row = rg * 4 + r, l = row >> 1, b = row & 1;
                float val = res[r] + bb;
                if (p == 0) {
                    q2[((size_t)b * L_SEQ + l) * E + col] = val;
                } else {
                    int h = col >> 5, d = col & 31;
                    float* dst = (p == 1) ? kh : vh;
                    dst[((size_t)(b * NH + h) * L_SEQ + l) * HD + d] = val;
                }
            }
        }
    }
}

// ---------------- Kernel 2: QK^T * scale + mask -> scores ----------------
// grid (16 heads, 64 l-grps) -> 1024 blocks (4/CU). k rows in registers.
__global__ void qk_kernel(const float* __restrict__ q2,
                          const float* __restrict__ kh,
                          const float* __restrict__ mask,
                          float* __restrict__ scores) {
    int n = blockIdx.x;              // 0..15
    int b = n >> 3, h = n & 7;
    int l0 = blockIdx.y * 8;
    int t = threadIdx.x, lane = t & 63, w = t >> 6;

    __shared__ float qs[8][32];
    if (t < 64) {
        int row = t >> 3, quad = t & 7;
        float4 qv = *(const float4*)(q2 + ((size_t)b * L_SEQ + l0 + row) * E + h * HD + quad * 4);
        ((float4*)qs[row])[quad] = qv;
    }
    __syncthreads();

    f32x4 ka[8], kb[8];
    const float* kbase = kh + (size_t)n * L_SEQ * HD;
    {
        const f32x4* pa = (const f32x4*)(kbase + (size_t)(w * 128 + lane) * HD);
        const f32x4* pb = (const f32x4*)(kbase + (size_t)(w * 128 + 64 + lane) * HD);
#pragma unroll
        for (int i = 0; i < 8; ++i) { ka[i] = pa[i]; kb[i] = pb[i]; }
    }

#pragma unroll
    for (int li = 0; li < 8; ++li) {
        int l = l0 + li;
        float da = 0.f, db = 0.f;
#pragma unroll
        for (int i = 0; i < 8; ++i) {
            float4 qv = ((const float4*)qs[li])[i];
            da += ka[i].x * qv.x + ka[i].y * qv.y + ka[i].z * qv.z + ka[i].w * qv.w;
            db += kb[i].x * qv.x + kb[i].y * qv.y + kb[i].z * qv.z + kb[i].w * qv.w;
        }
        size_t off = ((size_t)n * L_SEQ + l) * L_SEQ;
        const float* mrow = mask + (size_t)l * L_SEQ;
        scores[off + w * 128 + lane]      = da * SCALE + mrow[w * 128 + lane];
        scores[off + w * 128 + 64 + lane] = db * SCALE + mrow[w * 128 + 64 + lane];
    }
}

// ---------------- Kernel 3: rel-bias stream + softmax -> attn ----------------
// One block per (b,l), 512 thr = 8 waves. Streams ONLY rpe (regular loads,
// nt dropped: A/B test) + 16KB scores; writes attn. No reused tensors here.
__global__ void relattn_kernel(const float* __restrict__ q2,
                               const float* __restrict__ rpe,
                               const float* __restrict__ scores,
                               float* __restrict__ attn_out) {
    int bid = blockIdx.x;            // b*512 + l
    int b = bid >> 9, l = bid & (L_SEQ - 1);
    int t = threadIdx.x;
    int lane = t & 63, wid = t >> 6;

    __shared__ float qs[E];
    __shared__ float s_lds[NH * SROW];

    if (t < E) qs[t] = q2[((size_t)b * L_SEQ + l) * E + t];
    __syncthreads();

    // Phase 1: wave w streams rows m = w*64 .. w*64+63 (64KB contiguous).
    f32x4 qc = ((const f32x4*)qs)[lane];   // head lane>>3, quad lane&7
    int h1 = lane >> 3;
    const float* rbase = rpe + ((size_t)(b * L_SEQ + l)) * L_SEQ * E;

#pragma unroll 8
    for (int i = 0; i < 64; ++i) {
        int m = wid * 64 + i;
        f32x4 rv = *(((const f32x4*)(rbase + (size_t)m * E)) + lane);
        float part = rv.x * qc.x + rv.y * qc.y + rv.z * qc.z + rv.w * qc.w;
        part += __shfl_xor(part, 1);
        part += __shfl_xor(part, 2);
        part += __shfl_xor(part, 4);
        if ((lane & 7) == 0) s_lds[h1 * SROW + m] = part;
    }
    __syncthreads();

    // Phase 2: softmax; wave w owns head w.
    int h = wid;
    const float* srow = scores + ((size_t)(b * NH + h) * L_SEQ + l) * L_SEQ;
    float sv[8];
    float mx = -1e30f;
#pragma unroll
    for (int i = 0; i < 8; ++i) {
        int m = i * 64 + lane;
        sv[i] = s_lds[h * SROW + m] + srow[m];
        mx = fmaxf(mx, sv[i]);
    }
#pragma unroll
    for (int off = 32; off > 0; off >>= 1) mx = fmaxf(mx, __shfl_xor(mx, off));
    float sum = 0.f;
#pragma unroll
    for (int i = 0; i < 8; ++i) { sv[i] = __expf(sv[i] - mx); sum += sv[i]; }
#pragma unroll
    for (int off = 32; off > 0; off >>= 1) sum += __shfl_xor(sum, off);
    float inv = 1.0f / sum;

    float* arow = attn_out + ((size_t)(b * NH + h) * L_SEQ + l) * L_SEQ;
#pragma unroll
    for (int i = 0; i < 8; ++i) {
        arow[i * 64 + lane] = sv[i] * inv;
    }
}

// ---------------- Kernel 4: PV (attn @ v) ----------------
// grid (16 heads, 32 l-grps) -> 512 blocks (2/CU). v staged in LDS (XOR-swizzled
// quads: conflict-free b128 reads), reused across 16 l's.
__global__ void pv_kernel(const float* __restrict__ attn,
                          const float* __restrict__ vh,
                          float* __restrict__ oh2) {
    int n = blockIdx.x;              // 0..15
    int b = n >> 3, h = n & 7;
    int lg = blockIdx.y;             // l's lg*16 .. +15
    int t = threadIdx.x;             // 0..255

    __shared__ float vlds[L_SEQ * HD];   // swizzled: row m, quad slot (dq ^ (m&7))
    __shared__ float pl[L_SEQ];
    __shared__ float red[32][33];

    const f32x4* vsrc = (const f32x4*)(vh + (size_t)n * L_SEQ * HD);
#pragma unroll
    for (int j = 0; j < 16; ++j) {
        int qg = j * 256 + t;            // global quad index 0..4095
        int m = qg >> 3, dq = qg & 7;
        f32x4 v4 = vsrc[qg];
        int qsw = dq ^ (m & 7);
        *(f32x4*)&vlds[m * HD + qsw * 4] = v4;
    }
    __syncthreads();

    int mg = t >> 3, dq = t & 7;         // mg 0..31; per-thread m = i*32+mg
    int qsw = dq ^ (mg & 7);             // (i*32+mg)&7 == mg&7
    for (int li = 0; li < 16; ++li) {
        int l = lg * 16 + li;
        const float2* prow = (const float2*)(attn + ((size_t)n * L_SEQ + l) * L_SEQ);
        *(float2*)&pl[t * 2] = prow[t];
        __syncthreads();

        float ax = 0.f, ay = 0.f, az = 0.f, aw = 0.f;
#pragma unroll
        for (int i = 0; i < 16; ++i) {
            int m = i * 32 + mg;
            f32x4 v4 = *(const f32x4*)&vlds[m * HD + qsw * 4];
            float p = pl[m];
            ax += p * v4.x; ay += p * v4.y; az += p * v4.z; aw += p * v4.w;
        }
        red[mg][dq * 4 + 0] = ax;
        red[mg][dq * 4 + 1] = ay;
        red[mg][dq * 4 + 2] = az;
        red[mg][dq * 4 + 3] = aw;
        __syncthreads();

        if (t < 32) {
            float s = 0.f;
#pragma unroll
            for (int g = 0; g < 32; ++g) s += red[g][t];
            // de-swizzle: red column index t was written as dq*4+j with the
            // SAME (dq,j) mapping for every mg since qsw only permutes LDS
            // banks, not the accumulator layout -> column t == d directly.
            oh2[((size_t)b * L_SEQ + l) * E + h * HD + t] = s;
        }
        __syncthreads();
    }
}

// ---------------- Kernel 5: out-projection ----------------
// grid (256 rowgrps, 4 colgrps) -> 1024 blocks. Block: 4 rows x 64 cols.
__global__ void outproj_kernel(const float* __restrict__ oh2,
                               const float* __restrict__ W,
                               const float* __restrict__ bias,
                               float* __restrict__ out) {
    int rg = blockIdx.x;
    int cg3 = blockIdx.y;            // cols cg3*64 .. +63
    int t = threadIdx.x;
    __shared__ float xs[4][E];
#pragma unroll
    for (int r = 0; r < 4; ++r) {
        int row = rg * 4 + r, l = row >> 1, b = row & 1;
        xs[r][t] = oh2[((size_t)b * L_SEQ + l) * E + t];
    }
    __syncthreads();

    int c = t & 7, cg = t >> 3;
#pragma unroll
    for (int pp = 0; pp < 2; ++pp) {
        int col = cg3 * 64 + pp * 32 + cg;
        const float4* wp = (const float4*)(W + (size_t)col * E);
        float a0 = 0.f, a1 = 0.f, a2 = 0.f, a3 = 0.f;
#pragma unroll
        for (int kk = 0; kk < 8; ++kk) {
            float4 w  = wp[c + kk * 8];
            float4 x0 = ((const float4*)xs[0])[c + kk * 8];
            float4 x1 = ((const float4*)xs[1])[c + kk * 8];
            float4 x2 = ((const float4*)xs[2])[c + kk * 8];
            float4 x3 = ((const float4*)xs[3])[c + kk * 8];
            a0 += w.x * x0.x + w.y * x0.y + w.z * x0.z + w.w * x0.w;
            a1 += w.x * x1.x + w.y * x1.y + w.z * x1.z + w.w * x1.w;
            a2 += w.x * x2.x + w.y * x2.y + w.z * x2.z + w.w * x2.w;
            a3 += w.x * x3.x + w.y * x3.y + w.z * x3.z + w.w * x3.w;
        }
#pragma unroll
        for (int off = 1; off <= 4; off <<= 1) {
            a0 += __shfl_xor(a0, off);
            a1 += __shfl_xor(a1, off);
            a2 += __shfl_xor(a2, off);
            a3 += __shfl_xor(a3, off);
        }
        if (c == 0) {
            float bb = bias[col];
            float res[4] = {a0, a1, a2, a3};
#pragma unroll
            for (int r = 0; r < 4; ++r) {
                out[(size_t)(rg * 4 + r) * E + col] = res[r] + bb;
            }
        }
    }
}

extern "C" void kernel_launch(void* const* d_in, const int* in_sizes, int n_in,
                              void* d_out, int out_size, void* d_ws, size_t ws_size,
                              hipStream_t stream) {
    const float* query = (const float*)d_in[0];
    // d_in[1] = key, d_in[2] = value -- UNUSED (reference projects only query)
    const float* rpe   = (const float*)d_in[3];
    const float* mask  = (const float*)d_in[4];
    const float* Win   = (const float*)d_in[5];
    const float* bin   = (const float*)d_in[6];
    const float* Wout  = (const float*)d_in[7];
    const float* bout  = (const float*)d_in[8];

    float* out  = (float*)d_out;                            // (L,B,E)
    float* attn = (float*)d_out + (size_t)L_SEQ * BSZ * E;  // (B*H,L,L)

    float* q2     = (float*)d_ws;                           // (B,L,E)
    float* kh     = q2  + (size_t)BSZ * L_SEQ * E;          // (B*H,L,D)
    float* vh     = kh  + (size_t)BSZ * NH * L_SEQ * HD;    // (B*H,L,D)
    float* oh2    = vh  + (size_t)BSZ * NH * L_SEQ * HD;    // (B,L,E)
    float* scores = oh2 + (size_t)BSZ * L_SEQ * E;          // (B*H,L,L)

    inproj_kernel<<<dim3(256, 12), 256, 0, stream>>>(query, Win, bin, q2, kh, vh);
    qk_kernel<<<dim3(BSZ * NH, 64), 256, 0, stream>>>(q2, kh, mask, scores);
    relattn_kernel<<<BSZ * L_SEQ, 512, 0, stream>>>(q2, rpe, scores, attn);
    pv_kernel<<<dim3(BSZ * NH, 32), 256, 0, stream>>>(attn, vh, oh2);
    outproj_kernel<<<dim3(256, 4), 256, 0, stream>>>(oh2, Wout, bout, out);
}